// Round 12
// baseline (370.817 us; speedup 1.0000x reference)
//
#include <hip/hip_runtime.h>
#include <cstdint>
#include <cstddef>

#define BB 32
#define AA 8400
#define NBB 32
#define CC 80
#define TOPKN 10

// ===========================================================================
// MEASUREMENT-PROBE ROUND: each kernel repeats its (idempotent) body nrep
// times so per-kernel cost = row_dur/nrep becomes visible in the top-5
// dispatch table. asm volatile opaque ops block LICM from hoisting the
// rep-invariant compute. Semantics identical to R11 (validated absmax 0.0).
// ===========================================================================

// K1: per (b,j) block (256t): analytic candidate enumeration + top-10.
__global__ __launch_bounds__(256) void gt_topk_kernel(
    const float* __restrict__ pred_scores, const float* __restrict__ pred_boxes,
    const int* __restrict__ gt_labels, const float* __restrict__ gt_boxes,
    const int* __restrict__ gt_mask,
    int* __restrict__ tk, int* __restrict__ posA, int* __restrict__ posI,
    int* __restrict__ assign_ws, int nrep) {
  const int j = blockIdx.x, b = blockIdx.y, t = threadIdx.x;

  __shared__ unsigned long long s_key[256][TOPKN + 1];  // stride 88B

  for (int rep = 0; rep < nrep; ++rep) {
    int g = b * NBB + j;
    asm volatile("" : "+v"(g));  // opaque: make downstream rep-variant

    if (t == 0) { posA[g] = 0; posI[g] = 0; }
    {
      const int idx = g * 256 + t;
      if (idx < (BB * AA) / 4)
        reinterpret_cast<int4*>(assign_ws)[idx] = make_int4(-1, -1, -1, -1);
    }

    const float gx0 = gt_boxes[g * 4 + 0], gy0 = gt_boxes[g * 4 + 1];
    const float gx1 = gt_boxes[g * 4 + 2], gy1 = gt_boxes[g * 4 + 3];
    const int cls = gt_labels[g];
    const bool valid = (gt_mask[g] != 0);
    const float ga1 = (gx1 - gx0) * (gy1 - gy0);

    unsigned long long tkkey[TOPKN];
#pragma unroll
    for (int k = 0; k < TOPKN; k++) tkkey[k] = 0ull;

    if (valid) {
      const int strides[3] = {8, 16, 32};
      const int grids[3] = {80, 40, 20};
      const int offs[3] = {0, 6400, 8000};
      for (int lvl = 0; lvl < 3; lvl++) {
        const float s = (float)strides[lvl];
        const int n = grids[lvl], off = offs[lvl];
        int lx = max(0, (int)floorf(gx0 / s - 0.5f) - 1);
        int hx = min(n - 1, (int)ceilf(gx1 / s - 0.5f) + 1);
        int ly = max(0, (int)floorf(gy0 / s - 0.5f) - 1);
        int hy = min(n - 1, (int)ceilf(gy1 / s - 0.5f) + 1);
        if (hx < lx || hy < ly) continue;
        const int w = hx - lx + 1;
        const int m = w * (hy - ly + 1);
        for (int i = t; i < m; i += 256) {
          const int ix = lx + i % w;
          const int iy = ly + i / w;
          const float apx = ((float)ix + 0.5f) * s;
          const float apy = ((float)iy + 0.5f) * s;
          const float d = fminf(fminf(apx - gx0, apy - gy0),
                                fminf(gx1 - apx, gy1 - apy));
          if (!(d > 1e-8f)) continue;
          const int a = off + iy * n + ix;
          const float* pb = pred_boxes + ((size_t)b * AA + a) * 4;
          const float p0 = pb[0], p1 = pb[1], p2 = pb[2], p3 = pb[3];
          const float iw = fmaxf(fminf(gx1, p2) - fmaxf(gx0, p0), 0.0f);
          const float ih = fmaxf(fminf(gy1, p3) - fmaxf(gy0, p1), 0.0f);
          const float inter = iw * ih;
          const float a2 = (p2 - p0) * (p3 - p1);
          const float iou = fmaxf(inter / (ga1 + a2 - inter + 1e-10f), 0.0f);
          const float sc = pred_scores[((size_t)b * AA + a) * CC + cls];
          const float i2 = iou * iou;
          const float align_v = sc * i2 * i2 * i2;
          const unsigned long long key =
              ((unsigned long long)__float_as_uint(align_v) << 32) |
              (unsigned int)(AA - a);
          if (key > tkkey[TOPKN - 1]) {
            tkkey[TOPKN - 1] = key;
#pragma unroll
            for (int k = TOPKN - 1; k > 0; k--) {
              if (tkkey[k] > tkkey[k - 1]) {
                unsigned long long tmp = tkkey[k];
                tkkey[k] = tkkey[k - 1];
                tkkey[k - 1] = tmp;
              }
            }
          }
        }
      }
    }

#pragma unroll
    for (int k = 0; k < TOPKN; k++) s_key[t][k] = tkkey[k];
    __syncthreads();

    for (int stride = 128; stride >= 1; stride >>= 1) {
      if (t < stride) {
        unsigned long long mk[TOPKN];
        int p = 0, q = 0;
#pragma unroll
        for (int k = 0; k < TOPKN; k++) {
          const unsigned long long k1 = s_key[t][p], k2 = s_key[t + stride][q];
          if (k1 >= k2) { mk[k] = k1; p++; } else { mk[k] = k2; q++; }
        }
#pragma unroll
        for (int k = 0; k < TOPKN; k++) s_key[t][k] = mk[k];
      }
      __syncthreads();
    }

    if (t < TOPKN) {
      const unsigned long long key = s_key[0][t];
      tk[g * TOPKN + t] = (key != 0ull) ? (AA - (int)(key & 0xffffffffu)) : -1;
    }
    __syncthreads();  // WAR on s_key before next rep
  }
}

// K2 (sparse): one block per batch; only top-10 candidates processed.
__global__ __launch_bounds__(256) void assign_sparse_kernel(
    const float* __restrict__ pred_scores, const float* __restrict__ pred_boxes,
    const float* __restrict__ anchor_points, const int* __restrict__ gt_labels,
    const float* __restrict__ gt_boxes, const int* __restrict__ gt_mask,
    const int* __restrict__ tk,
    int* __restrict__ assign_ws, float* __restrict__ align_ws,
    int* __restrict__ posA, int* __restrict__ posI, int nrep) {
  const int t = threadIdx.x;

  __shared__ float sbox[NBB][4];
  __shared__ int scls[NBB];
  __shared__ int svalid[NBB];
  __shared__ int sa[NBB * TOPKN];

  for (int rep = 0; rep < nrep; ++rep) {
    int b = blockIdx.x;
    asm volatile("" : "+v"(b));  // opaque

    if (t < NBB) {
      const int g = b * NBB + t;
      sbox[t][0] = gt_boxes[g * 4 + 0];
      sbox[t][1] = gt_boxes[g * 4 + 1];
      sbox[t][2] = gt_boxes[g * 4 + 2];
      sbox[t][3] = gt_boxes[g * 4 + 3];
      scls[t] = gt_labels[g];
      svalid[t] = (gt_mask[g] != 0) ? 1 : 0;
    }
    for (int e = t; e < NBB * TOPKN; e += 256) sa[e] = tk[b * NBB * TOPKN + e];
    __syncthreads();

    for (int e = t; e < NBB * TOPKN; e += 256) {
      const int a = sa[e];
      if (a < 0) continue;
      const int j = e / TOPKN;

      int cnt = 0;
      for (int q = 0; q < NBB * TOPKN; q++) cnt += (sa[q] == a) ? 1 : 0;

      const float apx = anchor_points[a * 2 + 0];
      const float apy = anchor_points[a * 2 + 1];
      const float* pb = pred_boxes + ((size_t)b * AA + a) * 4;
      const float p0 = pb[0], p1 = pb[1], p2 = pb[2], p3 = pb[3];
      const float a2 = (p2 - p0) * (p3 - p1);

      int jj;
      float iou_f;
      if (cnt == 1) {
        jj = j;
        const float gx0 = sbox[j][0], gy0 = sbox[j][1];
        const float gx1 = sbox[j][2], gy1 = sbox[j][3];
        const float iw = fmaxf(fminf(gx1, p2) - fmaxf(gx0, p0), 0.0f);
        const float ih = fmaxf(fminf(gy1, p3) - fmaxf(gy0, p1), 0.0f);
        const float inter = iw * ih;
        const float a1 = (gx1 - gx0) * (gy1 - gy0);
        iou_f = fmaxf(inter / (a1 + a2 - inter + 1e-10f), 0.0f);
      } else {
        float best_iou = -1.0f;
        int best_j = 0;
        for (int jq = 0; jq < NBB; jq++) {
          const float gx0 = sbox[jq][0], gy0 = sbox[jq][1];
          const float gx1 = sbox[jq][2], gy1 = sbox[jq][3];
          const float d = fminf(fminf(apx - gx0, apy - gy0),
                                fminf(gx1 - apx, gy1 - apy));
          float iou = 0.0f;
          if (svalid[jq] && d > 1e-8f) {
            const float iw = fmaxf(fminf(gx1, p2) - fmaxf(gx0, p0), 0.0f);
            const float ih = fmaxf(fminf(gy1, p3) - fmaxf(gy0, p1), 0.0f);
            const float inter = iw * ih;
            const float a1 = (gx1 - gx0) * (gy1 - gy0);
            iou = fmaxf(inter / (a1 + a2 - inter + 1e-10f), 0.0f);
          }
          if (iou > best_iou) { best_iou = iou; best_j = jq; }
        }
        jj = best_j;
        iou_f = best_iou;
      }

      const float sc = pred_scores[((size_t)b * AA + a) * CC + scls[jj]];
      const float i2 = iou_f * iou_f;
      const float align_v = sc * i2 * i2 * i2;
      assign_ws[b * AA + a] = jj;
      align_ws[b * AA + a] = align_v;
      atomicMax(&posA[b * NBB + jj], __float_as_int(align_v));
      atomicMax(&posI[b * NBB + jj], __float_as_int(iou_f));
    }
    __syncthreads();  // WAR on sa before next rep
  }
}

// K3: write the whole output.
__global__ __launch_bounds__(256) void write_out_kernel(
    const int* __restrict__ gt_labels, const float* __restrict__ gt_boxes,
    const int* __restrict__ assign_in, const float* __restrict__ align_in,
    const int* __restrict__ posA, const int* __restrict__ posI,
    float* __restrict__ out, int nrep) {
  for (int rep = 0; rep < nrep; ++rep) {
    int idx = blockIdx.x * 256 + threadIdx.x;
    asm volatile("" : "+v"(idx));  // opaque

    const int aidx = idx / 20;
    const int c = idx - aidx * 20;
    const int b = aidx / AA;

    const int assign = assign_in[aidx];
    const int j0 = (assign >= 0) ? assign : 0;
    const int g = b * NBB + j0;
    int label = gt_labels[g];
    label = min(max(label, 0), 80);

    float* out_scores = out + (size_t)BB * AA * 5;
    float4 vv = make_float4(0.f, 0.f, 0.f, 0.f);
    if (assign >= 0 && c == (label >> 2)) {
      const float pa = __int_as_float(posA[b * NBB + assign]);
      const float pi = __int_as_float(posI[b * NBB + assign]);
      const float norm = align_in[aidx] * pi / (pa + 1e-8f);
      ((float*)&vv)[label & 3] = norm;
    }
    reinterpret_cast<float4*>(out_scores)[(size_t)aidx * 20 + c] = vv;

    if (c == 0) {
      out[aidx] = (float)label;
      float* out_boxes = out + (size_t)BB * AA;
      out_boxes[(size_t)aidx * 4 + 0] = gt_boxes[g * 4 + 0];
      out_boxes[(size_t)aidx * 4 + 1] = gt_boxes[g * 4 + 1];
      out_boxes[(size_t)aidx * 4 + 2] = gt_boxes[g * 4 + 2];
      out_boxes[(size_t)aidx * 4 + 3] = gt_boxes[g * 4 + 3];
      out[(size_t)BB * AA * 85 + aidx] = (assign >= 0) ? 1.0f : 0.0f;
    }
  }
}

// ===========================================================================
extern "C" void kernel_launch(void* const* d_in, const int* in_sizes, int n_in,
                              void* d_out, int out_size, void* d_ws, size_t ws_size,
                              hipStream_t stream) {
  const float* pred_scores = (const float*)d_in[0];
  const float* pred_boxes = (const float*)d_in[1];
  const float* anchor_points = (const float*)d_in[2];
  const int* gt_labels = (const int*)d_in[3];
  const float* gt_boxes = (const float*)d_in[4];
  const int* gt_mask = (const int*)d_in[5];
  float* out = (float*)d_out;
  char* ws = (char*)d_ws;

  const int NREP = 8;  // measurement amplification (probe round)

  const size_t sz_acc = (size_t)BB * AA * 4;
  const size_t off_tk = 0;
  const size_t off_posA = off_tk + (size_t)BB * NBB * TOPKN * 4;
  const size_t off_posI = off_posA + 4096;
  const size_t off_assign = off_posI + 4096;
  const size_t off_align = off_assign + sz_acc;

  int* tk = (int*)(ws + off_tk);
  int* posA = (int*)(ws + off_posA);
  int* posI = (int*)(ws + off_posI);
  int* assign_ws = (int*)(ws + off_assign);
  float* align_ws = (float*)(ws + off_align);

  dim3 g1(NBB, BB);
  gt_topk_kernel<<<g1, 256, 0, stream>>>(pred_scores, pred_boxes, gt_labels,
                                         gt_boxes, gt_mask, tk, posA, posI,
                                         assign_ws, NREP);

  assign_sparse_kernel<<<BB, 256, 0, stream>>>(
      pred_scores, pred_boxes, anchor_points, gt_labels, gt_boxes, gt_mask,
      tk, assign_ws, align_ws, posA, posI, NREP);

  const int nchunks = BB * AA * 20;
  write_out_kernel<<<(nchunks + 255) / 256, 256, 0, stream>>>(
      gt_labels, gt_boxes, assign_ws, align_ws, posA, posI, out, NREP);
}

// Round 13
// 76.625 us; speedup vs baseline: 4.8394x; 4.8394x over previous
//
#include <hip/hip_runtime.h>
#include <cstdint>
#include <cstddef>

#define BB 32
#define AA 8400
#define NBB 32
#define CC 80
#define TOPKN 10

// ===========================================================================
// K1: per (b,j) block (256t). Analytic candidate enumeration (3-level grid,
// bit-exact (ix+0.5)*s recompute, exact d>1e-8 re-test) + block top-10 via
// padded LDS merge ([256][11] u64 rows). key = align_bits<<32 | (8400-a).
// Side duties: zero posA/posI, -1-fill assign_ws (1 int4/thread).
// ===========================================================================
__global__ __launch_bounds__(256) void gt_topk_kernel(
    const float* __restrict__ pred_scores, const float* __restrict__ pred_boxes,
    const int* __restrict__ gt_labels, const float* __restrict__ gt_boxes,
    const int* __restrict__ gt_mask,
    int* __restrict__ tk, int* __restrict__ posA, int* __restrict__ posI,
    int* __restrict__ assign_ws) {
  const int j = blockIdx.x, b = blockIdx.y, t = threadIdx.x;
  const int g = b * NBB + j;
  if (t == 0) { posA[g] = 0; posI[g] = 0; }
  {
    const int idx = g * 256 + t;
    if (idx < (BB * AA) / 4)
      reinterpret_cast<int4*>(assign_ws)[idx] = make_int4(-1, -1, -1, -1);
  }

  const float gx0 = gt_boxes[g * 4 + 0], gy0 = gt_boxes[g * 4 + 1];
  const float gx1 = gt_boxes[g * 4 + 2], gy1 = gt_boxes[g * 4 + 3];
  const int cls = gt_labels[g];
  const bool valid = (gt_mask[g] != 0);
  const float ga1 = (gx1 - gx0) * (gy1 - gy0);

  unsigned long long tkkey[TOPKN];
#pragma unroll
  for (int k = 0; k < TOPKN; k++) tkkey[k] = 0ull;

  if (valid) {
    const int strides[3] = {8, 16, 32};
    const int grids[3] = {80, 40, 20};
    const int offs[3] = {0, 6400, 8000};
    for (int lvl = 0; lvl < 3; lvl++) {
      const float s = (float)strides[lvl];
      const int n = grids[lvl], off = offs[lvl];
      int lx = max(0, (int)floorf(gx0 / s - 0.5f) - 1);
      int hx = min(n - 1, (int)ceilf(gx1 / s - 0.5f) + 1);
      int ly = max(0, (int)floorf(gy0 / s - 0.5f) - 1);
      int hy = min(n - 1, (int)ceilf(gy1 / s - 0.5f) + 1);
      if (hx < lx || hy < ly) continue;
      const int w = hx - lx + 1;
      const int m = w * (hy - ly + 1);
      for (int i = t; i < m; i += 256) {
        const int ix = lx + i % w;
        const int iy = ly + i / w;
        const float apx = ((float)ix + 0.5f) * s;
        const float apy = ((float)iy + 0.5f) * s;
        const float d = fminf(fminf(apx - gx0, apy - gy0),
                              fminf(gx1 - apx, gy1 - apy));
        if (!(d > 1e-8f)) continue;
        const int a = off + iy * n + ix;
        const float* pb = pred_boxes + ((size_t)b * AA + a) * 4;
        const float p0 = pb[0], p1 = pb[1], p2 = pb[2], p3 = pb[3];
        const float iw = fmaxf(fminf(gx1, p2) - fmaxf(gx0, p0), 0.0f);
        const float ih = fmaxf(fminf(gy1, p3) - fmaxf(gy0, p1), 0.0f);
        const float inter = iw * ih;
        const float a2 = (p2 - p0) * (p3 - p1);
        const float iou = fmaxf(inter / (ga1 + a2 - inter + 1e-10f), 0.0f);
        const float sc = pred_scores[((size_t)b * AA + a) * CC + cls];
        const float i2 = iou * iou;
        const float align_v = sc * i2 * i2 * i2;
        const unsigned long long key =
            ((unsigned long long)__float_as_uint(align_v) << 32) |
            (unsigned int)(AA - a);
        if (key > tkkey[TOPKN - 1]) {
          tkkey[TOPKN - 1] = key;
#pragma unroll
          for (int k = TOPKN - 1; k > 0; k--) {
            if (tkkey[k] > tkkey[k - 1]) {
              unsigned long long tmp = tkkey[k];
              tkkey[k] = tkkey[k - 1];
              tkkey[k - 1] = tmp;
            }
          }
        }
      }
    }
  }

  __shared__ unsigned long long s_key[256][TOPKN + 1];  // stride 88B: free
#pragma unroll
  for (int k = 0; k < TOPKN; k++) s_key[t][k] = tkkey[k];
  __syncthreads();

  for (int stride = 128; stride >= 1; stride >>= 1) {
    if (t < stride) {
      unsigned long long mk[TOPKN];
      int p = 0, q = 0;
#pragma unroll
      for (int k = 0; k < TOPKN; k++) {
        const unsigned long long k1 = s_key[t][p], k2 = s_key[t + stride][q];
        if (k1 >= k2) { mk[k] = k1; p++; } else { mk[k] = k2; q++; }
      }
#pragma unroll
      for (int k = 0; k < TOPKN; k++) s_key[t][k] = mk[k];
    }
    __syncthreads();
  }

  if (t < TOPKN) {
    const unsigned long long key = s_key[0][t];
    tk[g * TOPKN + t] = (key != 0ull) ? (AA - (int)(key & 0xffffffffu)) : -1;
  }
}

// ===========================================================================
// K2 (v3): grid (NBB, BB) x 64 threads -- 1024 blocks (R12 probe showed the
// 32-block version at 1.2% occupancy / 20 us, latency-bound). Each block
// owns gt row j's 10 candidate entries; batch's 320-entry list in LDS.
// cnt-scan addresses are wave-uniform -> LDS broadcast (conflict-free).
// cnt==1 -> row j; cnt>1 -> first-max argmax_j over all 32 gts (reference
// semantics). Duplicate-anchor writes across blocks are value-identical.
// ===========================================================================
__global__ __launch_bounds__(64) void assign_sparse_kernel(
    const float* __restrict__ pred_scores, const float* __restrict__ pred_boxes,
    const float* __restrict__ anchor_points, const int* __restrict__ gt_labels,
    const float* __restrict__ gt_boxes, const int* __restrict__ gt_mask,
    const int* __restrict__ tk,
    int* __restrict__ assign_ws, float* __restrict__ align_ws,
    int* __restrict__ posA, int* __restrict__ posI) {
  const int j = blockIdx.x, b = blockIdx.y, t = threadIdx.x;

  __shared__ float sbox[NBB][4];
  __shared__ int scls[NBB];
  __shared__ int svalid[NBB];
  __shared__ int sa[NBB * TOPKN];

  if (t < NBB) {
    const int g = b * NBB + t;
    sbox[t][0] = gt_boxes[g * 4 + 0];
    sbox[t][1] = gt_boxes[g * 4 + 1];
    sbox[t][2] = gt_boxes[g * 4 + 2];
    sbox[t][3] = gt_boxes[g * 4 + 3];
    scls[t] = gt_labels[g];
    svalid[t] = (gt_mask[g] != 0) ? 1 : 0;
  }
  for (int e = t; e < NBB * TOPKN; e += 64) sa[e] = tk[b * NBB * TOPKN + e];
  __syncthreads();

  if (t >= TOPKN) return;  // no further barriers below
  const int a = sa[j * TOPKN + t];
  if (a < 0) return;

  int cnt = 0;
  for (int q = 0; q < NBB * TOPKN; q++) cnt += (sa[q] == a) ? 1 : 0;

  const float apx = anchor_points[a * 2 + 0];
  const float apy = anchor_points[a * 2 + 1];
  const float* pb = pred_boxes + ((size_t)b * AA + a) * 4;
  const float p0 = pb[0], p1 = pb[1], p2 = pb[2], p3 = pb[3];
  const float a2 = (p2 - p0) * (p3 - p1);

  int jj;
  float iou_f;
  if (cnt == 1) {
    jj = j;
    const float gx0 = sbox[j][0], gy0 = sbox[j][1];
    const float gx1 = sbox[j][2], gy1 = sbox[j][3];
    const float iw = fmaxf(fminf(gx1, p2) - fmaxf(gx0, p0), 0.0f);
    const float ih = fmaxf(fminf(gy1, p3) - fmaxf(gy0, p1), 0.0f);
    const float inter = iw * ih;
    const float a1 = (gx1 - gx0) * (gy1 - gy0);
    iou_f = fmaxf(inter / (a1 + a2 - inter + 1e-10f), 0.0f);
  } else {
    float best_iou = -1.0f;
    int best_j = 0;
    for (int jq = 0; jq < NBB; jq++) {
      const float gx0 = sbox[jq][0], gy0 = sbox[jq][1];
      const float gx1 = sbox[jq][2], gy1 = sbox[jq][3];
      const float d = fminf(fminf(apx - gx0, apy - gy0),
                            fminf(gx1 - apx, gy1 - apy));
      float iou = 0.0f;
      if (svalid[jq] && d > 1e-8f) {
        const float iw = fmaxf(fminf(gx1, p2) - fmaxf(gx0, p0), 0.0f);
        const float ih = fmaxf(fminf(gy1, p3) - fmaxf(gy0, p1), 0.0f);
        const float inter = iw * ih;
        const float a1 = (gx1 - gx0) * (gy1 - gy0);
        iou = fmaxf(inter / (a1 + a2 - inter + 1e-10f), 0.0f);
      }
      if (iou > best_iou) { best_iou = iou; best_j = jq; }  // first-max
    }
    jj = best_j;
    iou_f = best_iou;
  }

  const float sc = pred_scores[((size_t)b * AA + a) * CC + scls[jj]];
  const float i2 = iou_f * iou_f;
  const float align_v = sc * i2 * i2 * i2;
  assign_ws[b * AA + a] = jj;
  align_ws[b * AA + a] = align_v;
  atomicMax(&posA[b * NBB + jj], __float_as_int(align_v));
  atomicMax(&posI[b * NBB + jj], __float_as_int(iou_f));
}

// ===========================================================================
// K3: write the whole output (unchanged, validated). One thread per float4
// chunk of the scores tensor (20/anchor); chunk-0 thread also writes
// label/box/fg.
// ===========================================================================
__global__ __launch_bounds__(256) void write_out_kernel(
    const int* __restrict__ gt_labels, const float* __restrict__ gt_boxes,
    const int* __restrict__ assign_in, const float* __restrict__ align_in,
    const int* __restrict__ posA, const int* __restrict__ posI,
    float* __restrict__ out) {
  const int idx = blockIdx.x * 256 + threadIdx.x;  // [0, BB*AA*20)
  const int aidx = idx / 20;
  const int c = idx - aidx * 20;
  const int b = aidx / AA;

  const int assign = assign_in[aidx];
  const int j0 = (assign >= 0) ? assign : 0;
  const int g = b * NBB + j0;
  int label = gt_labels[g];
  label = min(max(label, 0), 80);

  float* out_scores = out + (size_t)BB * AA * 5;
  float4 vv = make_float4(0.f, 0.f, 0.f, 0.f);
  if (assign >= 0 && c == (label >> 2)) {
    const float pa = __int_as_float(posA[b * NBB + assign]);
    const float pi = __int_as_float(posI[b * NBB + assign]);
    const float norm = align_in[aidx] * pi / (pa + 1e-8f);
    ((float*)&vv)[label & 3] = norm;
  }
  reinterpret_cast<float4*>(out_scores)[(size_t)aidx * 20 + c] = vv;

  if (c == 0) {
    out[aidx] = (float)label;
    float* out_boxes = out + (size_t)BB * AA;
    out_boxes[(size_t)aidx * 4 + 0] = gt_boxes[g * 4 + 0];
    out_boxes[(size_t)aidx * 4 + 1] = gt_boxes[g * 4 + 1];
    out_boxes[(size_t)aidx * 4 + 2] = gt_boxes[g * 4 + 2];
    out_boxes[(size_t)aidx * 4 + 3] = gt_boxes[g * 4 + 3];
    out[(size_t)BB * AA * 85 + aidx] = (assign >= 0) ? 1.0f : 0.0f;
  }
}

// ===========================================================================
extern "C" void kernel_launch(void* const* d_in, const int* in_sizes, int n_in,
                              void* d_out, int out_size, void* d_ws, size_t ws_size,
                              hipStream_t stream) {
  const float* pred_scores = (const float*)d_in[0];
  const float* pred_boxes = (const float*)d_in[1];
  const float* anchor_points = (const float*)d_in[2];
  const int* gt_labels = (const int*)d_in[3];
  const float* gt_boxes = (const float*)d_in[4];
  const int* gt_mask = (const int*)d_in[5];
  float* out = (float*)d_out;
  char* ws = (char*)d_ws;

  const size_t sz_acc = (size_t)BB * AA * 4;
  const size_t off_tk = 0;
  const size_t off_posA = off_tk + (size_t)BB * NBB * TOPKN * 4;
  const size_t off_posI = off_posA + 4096;
  const size_t off_assign = off_posI + 4096;
  const size_t off_align = off_assign + sz_acc;

  int* tk = (int*)(ws + off_tk);
  int* posA = (int*)(ws + off_posA);
  int* posI = (int*)(ws + off_posI);
  int* assign_ws = (int*)(ws + off_assign);
  float* align_ws = (float*)(ws + off_align);

  dim3 g1(NBB, BB);
  gt_topk_kernel<<<g1, 256, 0, stream>>>(pred_scores, pred_boxes, gt_labels,
                                         gt_boxes, gt_mask, tk, posA, posI,
                                         assign_ws);

  dim3 g2(NBB, BB);
  assign_sparse_kernel<<<g2, 64, 0, stream>>>(
      pred_scores, pred_boxes, anchor_points, gt_labels, gt_boxes, gt_mask,
      tk, assign_ws, align_ws, posA, posI);

  const int nchunks = BB * AA * 20;
  write_out_kernel<<<(nchunks + 255) / 256, 256, 0, stream>>>(
      gt_labels, gt_boxes, assign_ws, align_ws, posA, posI, out);
}

// Round 14
// 51.119 us; speedup vs baseline: 7.2540x; 1.4989x over previous
//
#include <hip/hip_runtime.h>
#include <cstdint>
#include <cstddef>

#define BB 32
#define AA 8400
#define NBB 32
#define CC 80
#define TOPKN 10

// ===========================================================================
// K3a: fill the ENTIRE output with "unassigned" defaults. Pure float4
// streaming store, no divergence: scores=0, fg=0, labels=clip(gt_labels[b,0]),
// boxes=gt_boxes[b,0]. Depends only on inputs -> first node. The sparse
// scatter (K3b) later overwrites the <=10k assigned anchors.
// Region float4 index map (NA=BB*AA; all region starts divisible by 4):
//   [0, NA/4)              labels   (8400%4==0 -> no batch straddling)
//   [NA/4, NA/4+NA)        boxes    (one float4 per anchor)
//   [.., +NA*20)           scores   (zeros)
//   [.., +NA/4)            fg       (zeros)
// ===========================================================================
__global__ __launch_bounds__(256) void fill_default_kernel(
    const int* __restrict__ gt_labels, const float* __restrict__ gt_boxes,
    float* __restrict__ out) {
  const int NA = BB * AA;
  const int labels4 = NA / 4;
  const int boxes4_end = labels4 + NA;
  const int total4 = labels4 + NA + NA * 20 + NA / 4;  // 5,779,200
  const int idx = blockIdx.x * 256 + threadIdx.x;
  if (idx >= total4) return;
  float4* o4 = reinterpret_cast<float4*>(out);
  if (idx < labels4) {
    const int b = (idx * 4) / AA;
    int lab = gt_labels[b * NBB];
    lab = min(max(lab, 0), 80);
    const float lf = (float)lab;
    o4[idx] = make_float4(lf, lf, lf, lf);
  } else if (idx < boxes4_end) {
    const int aidx = idx - labels4;
    const int b = aidx / AA;
    o4[idx] = *reinterpret_cast<const float4*>(gt_boxes + (size_t)b * NBB * 4);
  } else {
    o4[idx] = make_float4(0.f, 0.f, 0.f, 0.f);
  }
}

// ===========================================================================
// K1: per (b,j) block (256t). Analytic candidate enumeration (3-level grid,
// bit-exact (ix+0.5)*s recompute, exact d>1e-8 re-test) + block top-10 via
// padded LDS merge ([256][11] u64 rows, stride 88B). Zeroes posA/posI.
// key = align_bits<<32 | (8400-a): lax.top_k tie semantics.
// ===========================================================================
__global__ __launch_bounds__(256) void gt_topk_kernel(
    const float* __restrict__ pred_scores, const float* __restrict__ pred_boxes,
    const int* __restrict__ gt_labels, const float* __restrict__ gt_boxes,
    const int* __restrict__ gt_mask,
    int* __restrict__ tk, int* __restrict__ posA, int* __restrict__ posI) {
  const int j = blockIdx.x, b = blockIdx.y, t = threadIdx.x;
  const int g = b * NBB + j;
  if (t == 0) { posA[g] = 0; posI[g] = 0; }

  const float gx0 = gt_boxes[g * 4 + 0], gy0 = gt_boxes[g * 4 + 1];
  const float gx1 = gt_boxes[g * 4 + 2], gy1 = gt_boxes[g * 4 + 3];
  const int cls = gt_labels[g];
  const bool valid = (gt_mask[g] != 0);
  const float ga1 = (gx1 - gx0) * (gy1 - gy0);

  unsigned long long tkkey[TOPKN];
#pragma unroll
  for (int k = 0; k < TOPKN; k++) tkkey[k] = 0ull;

  if (valid) {
    const int strides[3] = {8, 16, 32};
    const int grids[3] = {80, 40, 20};
    const int offs[3] = {0, 6400, 8000};
    for (int lvl = 0; lvl < 3; lvl++) {
      const float s = (float)strides[lvl];
      const int n = grids[lvl], off = offs[lvl];
      int lx = max(0, (int)floorf(gx0 / s - 0.5f) - 1);
      int hx = min(n - 1, (int)ceilf(gx1 / s - 0.5f) + 1);
      int ly = max(0, (int)floorf(gy0 / s - 0.5f) - 1);
      int hy = min(n - 1, (int)ceilf(gy1 / s - 0.5f) + 1);
      if (hx < lx || hy < ly) continue;
      const int w = hx - lx + 1;
      const int m = w * (hy - ly + 1);
      for (int i = t; i < m; i += 256) {
        const int ix = lx + i % w;
        const int iy = ly + i / w;
        const float apx = ((float)ix + 0.5f) * s;
        const float apy = ((float)iy + 0.5f) * s;
        const float d = fminf(fminf(apx - gx0, apy - gy0),
                              fminf(gx1 - apx, gy1 - apy));
        if (!(d > 1e-8f)) continue;
        const int a = off + iy * n + ix;
        const float* pb = pred_boxes + ((size_t)b * AA + a) * 4;
        const float p0 = pb[0], p1 = pb[1], p2 = pb[2], p3 = pb[3];
        const float iw = fmaxf(fminf(gx1, p2) - fmaxf(gx0, p0), 0.0f);
        const float ih = fmaxf(fminf(gy1, p3) - fmaxf(gy0, p1), 0.0f);
        const float inter = iw * ih;
        const float a2 = (p2 - p0) * (p3 - p1);
        const float iou = fmaxf(inter / (ga1 + a2 - inter + 1e-10f), 0.0f);
        const float sc = pred_scores[((size_t)b * AA + a) * CC + cls];
        const float i2 = iou * iou;
        const float align_v = sc * i2 * i2 * i2;
        const unsigned long long key =
            ((unsigned long long)__float_as_uint(align_v) << 32) |
            (unsigned int)(AA - a);
        if (key > tkkey[TOPKN - 1]) {
          tkkey[TOPKN - 1] = key;
#pragma unroll
          for (int k = TOPKN - 1; k > 0; k--) {
            if (tkkey[k] > tkkey[k - 1]) {
              unsigned long long tmp = tkkey[k];
              tkkey[k] = tkkey[k - 1];
              tkkey[k - 1] = tmp;
            }
          }
        }
      }
    }
  }

  __shared__ unsigned long long s_key[256][TOPKN + 1];  // stride 88B: free
#pragma unroll
  for (int k = 0; k < TOPKN; k++) s_key[t][k] = tkkey[k];
  __syncthreads();

  for (int stride = 128; stride >= 1; stride >>= 1) {
    if (t < stride) {
      unsigned long long mk[TOPKN];
      int p = 0, q = 0;
#pragma unroll
      for (int k = 0; k < TOPKN; k++) {
        const unsigned long long k1 = s_key[t][p], k2 = s_key[t + stride][q];
        if (k1 >= k2) { mk[k] = k1; p++; } else { mk[k] = k2; q++; }
      }
#pragma unroll
      for (int k = 0; k < TOPKN; k++) s_key[t][k] = mk[k];
    }
    __syncthreads();
  }

  if (t < TOPKN) {
    const unsigned long long key = s_key[0][t];
    tk[g * TOPKN + t] = (key != 0ull) ? (AA - (int)(key & 0xffffffffu)) : -1;
  }
}

// ===========================================================================
// K2: grid (NBB, BB) x 64t (R12: 32-block version was 1.2% occupancy,
// 20 us). Block (j,b) resolves gt row j's 10 candidates against the batch's
// 320-entry LDS list. cnt==1 -> row j; cnt>1 -> first-max argmax_j over all
// 32 gts (reference semantics). Writes COMPACT per-entry results
// (resj/resAl) keyed by e = g*10+t; duplicates are value-identical.
// ===========================================================================
__global__ __launch_bounds__(64) void assign_sparse_kernel(
    const float* __restrict__ pred_scores, const float* __restrict__ pred_boxes,
    const float* __restrict__ anchor_points, const int* __restrict__ gt_labels,
    const float* __restrict__ gt_boxes, const int* __restrict__ gt_mask,
    const int* __restrict__ tk,
    int* __restrict__ resj, float* __restrict__ resAl,
    int* __restrict__ posA, int* __restrict__ posI) {
  const int j = blockIdx.x, b = blockIdx.y, t = threadIdx.x;

  __shared__ float sbox[NBB][4];
  __shared__ int scls[NBB];
  __shared__ int svalid[NBB];
  __shared__ int sa[NBB * TOPKN];

  if (t < NBB) {
    const int g = b * NBB + t;
    sbox[t][0] = gt_boxes[g * 4 + 0];
    sbox[t][1] = gt_boxes[g * 4 + 1];
    sbox[t][2] = gt_boxes[g * 4 + 2];
    sbox[t][3] = gt_boxes[g * 4 + 3];
    scls[t] = gt_labels[g];
    svalid[t] = (gt_mask[g] != 0) ? 1 : 0;
  }
  for (int e = t; e < NBB * TOPKN; e += 64) sa[e] = tk[b * NBB * TOPKN + e];
  __syncthreads();

  if (t >= TOPKN) return;  // no barriers below
  const int a = sa[j * TOPKN + t];
  if (a < 0) return;

  int cnt = 0;
  for (int q = 0; q < NBB * TOPKN; q++) cnt += (sa[q] == a) ? 1 : 0;

  const float apx = anchor_points[a * 2 + 0];
  const float apy = anchor_points[a * 2 + 1];
  const float* pb = pred_boxes + ((size_t)b * AA + a) * 4;
  const float p0 = pb[0], p1 = pb[1], p2 = pb[2], p3 = pb[3];
  const float a2 = (p2 - p0) * (p3 - p1);

  int jj;
  float iou_f;
  if (cnt == 1) {
    jj = j;
    const float gx0 = sbox[j][0], gy0 = sbox[j][1];
    const float gx1 = sbox[j][2], gy1 = sbox[j][3];
    const float iw = fmaxf(fminf(gx1, p2) - fmaxf(gx0, p0), 0.0f);
    const float ih = fmaxf(fminf(gy1, p3) - fmaxf(gy0, p1), 0.0f);
    const float inter = iw * ih;
    const float a1 = (gx1 - gx0) * (gy1 - gy0);
    iou_f = fmaxf(inter / (a1 + a2 - inter + 1e-10f), 0.0f);
  } else {
    float best_iou = -1.0f;
    int best_j = 0;
    for (int jq = 0; jq < NBB; jq++) {
      const float gx0 = sbox[jq][0], gy0 = sbox[jq][1];
      const float gx1 = sbox[jq][2], gy1 = sbox[jq][3];
      const float d = fminf(fminf(apx - gx0, apy - gy0),
                            fminf(gx1 - apx, gy1 - apy));
      float iou = 0.0f;
      if (svalid[jq] && d > 1e-8f) {
        const float iw = fmaxf(fminf(gx1, p2) - fmaxf(gx0, p0), 0.0f);
        const float ih = fmaxf(fminf(gy1, p3) - fmaxf(gy0, p1), 0.0f);
        const float inter = iw * ih;
        const float a1 = (gx1 - gx0) * (gy1 - gy0);
        iou = fmaxf(inter / (a1 + a2 - inter + 1e-10f), 0.0f);
      }
      if (iou > best_iou) { best_iou = iou; best_j = jq; }  // first-max
    }
    jj = best_j;
    iou_f = best_iou;
  }

  const float sc = pred_scores[((size_t)b * AA + a) * CC + scls[jj]];
  const float i2 = iou_f * iou_f;
  const float align_v = sc * i2 * i2 * i2;
  const int e = (b * NBB + j) * TOPKN + t;
  resj[e] = jj;
  resAl[e] = align_v;
  atomicMax(&posA[b * NBB + jj], __float_as_int(align_v));
  atomicMax(&posI[b * NBB + jj], __float_as_int(iou_f));
}

// ===========================================================================
// K3b: sparse scatter of assigned-anchor outputs over the defaults.
// One thread per candidate entry (10240). Duplicate entries (conflicted
// anchors listed in several rows) write identical values.
// ===========================================================================
__global__ __launch_bounds__(256) void scatter_out_kernel(
    const int* __restrict__ gt_labels, const float* __restrict__ gt_boxes,
    const int* __restrict__ tk, const int* __restrict__ resj,
    const float* __restrict__ resAl, const int* __restrict__ posA,
    const int* __restrict__ posI, float* __restrict__ out) {
  const int e = blockIdx.x * 256 + threadIdx.x;
  if (e >= BB * NBB * TOPKN) return;
  const int a = tk[e];
  if (a < 0) return;
  const int b = e / (NBB * TOPKN);
  const int jj = resj[e];
  const float align_v = resAl[e];
  const float pa = __int_as_float(posA[b * NBB + jj]);
  const float pi = __int_as_float(posI[b * NBB + jj]);
  const float norm = align_v * pi / (pa + 1e-8f);
  int label = gt_labels[b * NBB + jj];
  label = min(max(label, 0), 80);
  const size_t aidx = (size_t)b * AA + a;

  out[aidx] = (float)label;                                      // labels
  *reinterpret_cast<float4*>(out + (size_t)BB * AA + aidx * 4) = // boxes
      *reinterpret_cast<const float4*>(gt_boxes + ((size_t)b * NBB + jj) * 4);
  if (label < CC)
    out[(size_t)BB * AA * 5 + aidx * CC + label] = norm;         // scores
  out[(size_t)BB * AA * 85 + aidx] = 1.0f;                       // fg
}

// ===========================================================================
extern "C" void kernel_launch(void* const* d_in, const int* in_sizes, int n_in,
                              void* d_out, int out_size, void* d_ws, size_t ws_size,
                              hipStream_t stream) {
  const float* pred_scores = (const float*)d_in[0];
  const float* pred_boxes = (const float*)d_in[1];
  const float* anchor_points = (const float*)d_in[2];
  const int* gt_labels = (const int*)d_in[3];
  const float* gt_boxes = (const float*)d_in[4];
  const int* gt_mask = (const int*)d_in[5];
  float* out = (float*)d_out;
  char* ws = (char*)d_ws;

  // workspace: tk | posA | posI | resj | resAl (all small)
  const size_t off_tk = 0;                                  // 40 KB
  const size_t off_posA = off_tk + (size_t)BB * NBB * TOPKN * 4;
  const size_t off_posI = off_posA + 4096;
  const size_t off_resj = off_posI + 4096;                  // 40 KB
  const size_t off_resAl = off_resj + (size_t)BB * NBB * TOPKN * 4;

  int* tk = (int*)(ws + off_tk);
  int* posA = (int*)(ws + off_posA);
  int* posI = (int*)(ws + off_posI);
  int* resj = (int*)(ws + off_resj);
  float* resAl = (float*)(ws + off_resAl);

  // K3a: default-fill entire output (input-only deps)
  const int total4 = (BB * AA * 86) / 4;
  fill_default_kernel<<<(total4 + 255) / 256, 256, 0, stream>>>(
      gt_labels, gt_boxes, out);

  dim3 g1(NBB, BB);
  gt_topk_kernel<<<g1, 256, 0, stream>>>(pred_scores, pred_boxes, gt_labels,
                                         gt_boxes, gt_mask, tk, posA, posI);

  dim3 g2(NBB, BB);
  assign_sparse_kernel<<<g2, 64, 0, stream>>>(
      pred_scores, pred_boxes, anchor_points, gt_labels, gt_boxes, gt_mask,
      tk, resj, resAl, posA, posI);

  const int ncand = BB * NBB * TOPKN;
  scatter_out_kernel<<<(ncand + 255) / 256, 256, 0, stream>>>(
      gt_labels, gt_boxes, tk, resj, resAl, posA, posI, out);
}

// Round 16
// 48.908 us; speedup vs baseline: 7.5820x; 1.0452x over previous
//
#include <hip/hip_runtime.h>
#include <cstdint>
#include <cstddef>

#define BB 32
#define AA 8400
#define NBB 32
#define CC 80
#define TOPKN 10

// ===========================================================================
// K1 (+fused default-fill): per (b,j) block (256t).
// (1) Streams the "unassigned" default output for its 1/1024 slice of the
//     92.5 MB output (23 float4/thread, divergence-free) -- overlaps with
//     the latency-bound gathers of (2). Regions (float4 idx, NA=BB*AA):
//     [0,NA/4) labels=clip(gt_labels[b,0]) | [NA/4,NA/4+NA) boxes=gt_boxes[b,0]
//     | scores zeros | fg zeros.
// (2) Analytic candidate enumeration (3-level anchor grid, bit-exact
//     (ix+0.5)*s recompute, exact d>1e-8 re-test) + block top-10 via padded
//     LDS merge ([256][11] u64 rows, stride 88B -> free 2-way aliasing).
//     key = align_bits<<32 | (8400-a): lax.top_k tie semantics.
// Also zeroes posA/posI (t==0). K3b scatter later overwrites assigned rows.
// ===========================================================================
__global__ __launch_bounds__(256) void gt_topk_kernel(
    const float* __restrict__ pred_scores, const float* __restrict__ pred_boxes,
    const int* __restrict__ gt_labels, const float* __restrict__ gt_boxes,
    const int* __restrict__ gt_mask,
    int* __restrict__ tk, int* __restrict__ posA, int* __restrict__ posI,
    float* __restrict__ out) {
  const int j = blockIdx.x, b = blockIdx.y, t = threadIdx.x;
  const int g = b * NBB + j;
  if (t == 0) { posA[g] = 0; posI[g] = 0; }

  // ---- fused default-fill (write-only stream; no dependence on (2)) ----
  {
    const int NA = BB * AA;
    const int labels4 = NA / 4;
    const int boxes4_end = labels4 + NA;
    const int total4 = labels4 + NA + NA * 20 + NA / 4;  // 5,779,200
    float4* o4 = reinterpret_cast<float4*>(out);
    for (int idx = (g << 8) + t; idx < total4; idx += 1024 * 256) {
      if (idx < labels4) {
        const int fb = (idx * 4) / AA;
        int lab = gt_labels[fb * NBB];
        lab = min(max(lab, 0), 80);
        const float lf = (float)lab;
        o4[idx] = make_float4(lf, lf, lf, lf);
      } else if (idx < boxes4_end) {
        const int aidx = idx - labels4;
        const int fb = aidx / AA;
        o4[idx] =
            *reinterpret_cast<const float4*>(gt_boxes + (size_t)fb * NBB * 4);
      } else {
        o4[idx] = make_float4(0.f, 0.f, 0.f, 0.f);
      }
    }
  }

  // ---- candidate enumeration + top-10 ----
  const float gx0 = gt_boxes[g * 4 + 0], gy0 = gt_boxes[g * 4 + 1];
  const float gx1 = gt_boxes[g * 4 + 2], gy1 = gt_boxes[g * 4 + 3];
  const int cls = gt_labels[g];
  const bool valid = (gt_mask[g] != 0);
  const float ga1 = (gx1 - gx0) * (gy1 - gy0);

  unsigned long long tkkey[TOPKN];
#pragma unroll
  for (int k = 0; k < TOPKN; k++) tkkey[k] = 0ull;

  if (valid) {
    const int strides[3] = {8, 16, 32};
    const int grids[3] = {80, 40, 20};
    const int offs[3] = {0, 6400, 8000};
    for (int lvl = 0; lvl < 3; lvl++) {
      const float s = (float)strides[lvl];
      const int n = grids[lvl], off = offs[lvl];
      int lx = max(0, (int)floorf(gx0 / s - 0.5f) - 1);
      int hx = min(n - 1, (int)ceilf(gx1 / s - 0.5f) + 1);
      int ly = max(0, (int)floorf(gy0 / s - 0.5f) - 1);
      int hy = min(n - 1, (int)ceilf(gy1 / s - 0.5f) + 1);
      if (hx < lx || hy < ly) continue;
      const int w = hx - lx + 1;
      const int m = w * (hy - ly + 1);
      for (int i = t; i < m; i += 256) {
        const int ix = lx + i % w;
        const int iy = ly + i / w;
        const float apx = ((float)ix + 0.5f) * s;
        const float apy = ((float)iy + 0.5f) * s;
        const float d = fminf(fminf(apx - gx0, apy - gy0),
                              fminf(gx1 - apx, gy1 - apy));
        if (!(d > 1e-8f)) continue;
        const int a = off + iy * n + ix;
        const float* pb = pred_boxes + ((size_t)b * AA + a) * 4;
        const float p0 = pb[0], p1 = pb[1], p2 = pb[2], p3 = pb[3];
        const float iw = fmaxf(fminf(gx1, p2) - fmaxf(gx0, p0), 0.0f);
        const float ih = fmaxf(fminf(gy1, p3) - fmaxf(gy0, p1), 0.0f);
        const float inter = iw * ih;
        const float a2 = (p2 - p0) * (p3 - p1);
        const float iou = fmaxf(inter / (ga1 + a2 - inter + 1e-10f), 0.0f);
        const float sc = pred_scores[((size_t)b * AA + a) * CC + cls];
        const float i2 = iou * iou;
        const float align_v = sc * i2 * i2 * i2;
        const unsigned long long key =
            ((unsigned long long)__float_as_uint(align_v) << 32) |
            (unsigned int)(AA - a);
        if (key > tkkey[TOPKN - 1]) {
          tkkey[TOPKN - 1] = key;
#pragma unroll
          for (int k = TOPKN - 1; k > 0; k--) {
            if (tkkey[k] > tkkey[k - 1]) {
              unsigned long long tmp = tkkey[k];
              tkkey[k] = tkkey[k - 1];
              tkkey[k - 1] = tmp;
            }
          }
        }
      }
    }
  }

  __shared__ unsigned long long s_key[256][TOPKN + 1];  // stride 88B: free
#pragma unroll
  for (int k = 0; k < TOPKN; k++) s_key[t][k] = tkkey[k];
  __syncthreads();

  for (int stride = 128; stride >= 1; stride >>= 1) {
    if (t < stride) {
      unsigned long long mk[TOPKN];
      int p = 0, q = 0;
#pragma unroll
      for (int k = 0; k < TOPKN; k++) {
        const unsigned long long k1 = s_key[t][p], k2 = s_key[t + stride][q];
        if (k1 >= k2) { mk[k] = k1; p++; } else { mk[k] = k2; q++; }
      }
#pragma unroll
      for (int k = 0; k < TOPKN; k++) s_key[t][k] = mk[k];
    }
    __syncthreads();
  }

  if (t < TOPKN) {
    const unsigned long long key = s_key[0][t];
    tk[g * TOPKN + t] = (key != 0ull) ? (AA - (int)(key & 0xffffffffu)) : -1;
  }
}

// ===========================================================================
// K2: grid (NBB, BB) x 64t. Block (j,b) resolves gt row j's 10 candidates
// against the batch's 320-entry LDS list (wave-uniform scan = LDS
// broadcast). cnt==1 -> row j; cnt>1 -> first-max argmax_j over all 32 gts.
// Writes COMPACT per-entry results (resj/resAl); duplicates value-identical.
// ===========================================================================
__global__ __launch_bounds__(64) void assign_sparse_kernel(
    const float* __restrict__ pred_scores, const float* __restrict__ pred_boxes,
    const float* __restrict__ anchor_points, const int* __restrict__ gt_labels,
    const float* __restrict__ gt_boxes, const int* __restrict__ gt_mask,
    const int* __restrict__ tk,
    int* __restrict__ resj, float* __restrict__ resAl,
    int* __restrict__ posA, int* __restrict__ posI) {
  const int j = blockIdx.x, b = blockIdx.y, t = threadIdx.x;

  __shared__ float sbox[NBB][4];
  __shared__ int scls[NBB];
  __shared__ int svalid[NBB];
  __shared__ int sa[NBB * TOPKN];

  if (t < NBB) {
    const int g = b * NBB + t;
    sbox[t][0] = gt_boxes[g * 4 + 0];
    sbox[t][1] = gt_boxes[g * 4 + 1];
    sbox[t][2] = gt_boxes[g * 4 + 2];
    sbox[t][3] = gt_boxes[g * 4 + 3];
    scls[t] = gt_labels[g];
    svalid[t] = (gt_mask[g] != 0) ? 1 : 0;
  }
  for (int e = t; e < NBB * TOPKN; e += 64) sa[e] = tk[b * NBB * TOPKN + e];
  __syncthreads();

  if (t >= TOPKN) return;  // no barriers below
  const int a = sa[j * TOPKN + t];
  if (a < 0) return;

  int cnt = 0;
  for (int q = 0; q < NBB * TOPKN; q++) cnt += (sa[q] == a) ? 1 : 0;

  const float apx = anchor_points[a * 2 + 0];
  const float apy = anchor_points[a * 2 + 1];
  const float* pb = pred_boxes + ((size_t)b * AA + a) * 4;
  const float p0 = pb[0], p1 = pb[1], p2 = pb[2], p3 = pb[3];
  const float a2 = (p2 - p0) * (p3 - p1);

  int jj;
  float iou_f;
  if (cnt == 1) {
    jj = j;
    const float gx0 = sbox[j][0], gy0 = sbox[j][1];
    const float gx1 = sbox[j][2], gy1 = sbox[j][3];
    const float iw = fmaxf(fminf(gx1, p2) - fmaxf(gx0, p0), 0.0f);
    const float ih = fmaxf(fminf(gy1, p3) - fmaxf(gy0, p1), 0.0f);
    const float inter = iw * ih;
    const float a1 = (gx1 - gx0) * (gy1 - gy0);
    iou_f = fmaxf(inter / (a1 + a2 - inter + 1e-10f), 0.0f);
  } else {
    float best_iou = -1.0f;
    int best_j = 0;
    for (int jq = 0; jq < NBB; jq++) {
      const float gx0 = sbox[jq][0], gy0 = sbox[jq][1];
      const float gx1 = sbox[jq][2], gy1 = sbox[jq][3];
      const float d = fminf(fminf(apx - gx0, apy - gy0),
                            fminf(gx1 - apx, gy1 - apy));
      float iou = 0.0f;
      if (svalid[jq] && d > 1e-8f) {
        const float iw = fmaxf(fminf(gx1, p2) - fmaxf(gx0, p0), 0.0f);
        const float ih = fmaxf(fminf(gy1, p3) - fmaxf(gy0, p1), 0.0f);
        const float inter = iw * ih;
        const float a1 = (gx1 - gx0) * (gy1 - gy0);
        iou = fmaxf(inter / (a1 + a2 - inter + 1e-10f), 0.0f);
      }
      if (iou > best_iou) { best_iou = iou; best_j = jq; }  // first-max
    }
    jj = best_j;
    iou_f = best_iou;
  }

  const float sc = pred_scores[((size_t)b * AA + a) * CC + scls[jj]];
  const float i2 = iou_f * iou_f;
  const float align_v = sc * i2 * i2 * i2;
  const int e = (b * NBB + j) * TOPKN + t;
  resj[e] = jj;
  resAl[e] = align_v;
  atomicMax(&posA[b * NBB + jj], __float_as_int(align_v));
  atomicMax(&posI[b * NBB + jj], __float_as_int(iou_f));
}

// ===========================================================================
// K3b: sparse scatter of assigned-anchor outputs over the defaults.
// One thread per candidate entry (10240). Duplicate entries value-identical.
// ===========================================================================
__global__ __launch_bounds__(256) void scatter_out_kernel(
    const int* __restrict__ gt_labels, const float* __restrict__ gt_boxes,
    const int* __restrict__ tk, const int* __restrict__ resj,
    const float* __restrict__ resAl, const int* __restrict__ posA,
    const int* __restrict__ posI, float* __restrict__ out) {
  const int e = blockIdx.x * 256 + threadIdx.x;
  if (e >= BB * NBB * TOPKN) return;
  const int a = tk[e];
  if (a < 0) return;
  const int b = e / (NBB * TOPKN);
  const int jj = resj[e];
  const float align_v = resAl[e];
  const float pa = __int_as_float(posA[b * NBB + jj]);
  const float pi = __int_as_float(posI[b * NBB + jj]);
  const float norm = align_v * pi / (pa + 1e-8f);
  int label = gt_labels[b * NBB + jj];
  label = min(max(label, 0), 80);
  const size_t aidx = (size_t)b * AA + a;

  out[aidx] = (float)label;                                       // labels
  *reinterpret_cast<float4*>(out + (size_t)BB * AA + aidx * 4) =  // boxes
      *reinterpret_cast<const float4*>(gt_boxes + ((size_t)b * NBB + jj) * 4);
  if (label < CC)
    out[(size_t)BB * AA * 5 + aidx * CC + label] = norm;          // scores
  out[(size_t)BB * AA * 85 + aidx] = 1.0f;                        // fg
}

// ===========================================================================
extern "C" void kernel_launch(void* const* d_in, const int* in_sizes, int n_in,
                              void* d_out, int out_size, void* d_ws, size_t ws_size,
                              hipStream_t stream) {
  const float* pred_scores = (const float*)d_in[0];
  const float* pred_boxes = (const float*)d_in[1];
  const float* anchor_points = (const float*)d_in[2];
  const int* gt_labels = (const int*)d_in[3];
  const float* gt_boxes = (const float*)d_in[4];
  const int* gt_mask = (const int*)d_in[5];
  float* out = (float*)d_out;
  char* ws = (char*)d_ws;

  // workspace: tk | posA | posI | resj | resAl (all small)
  const size_t off_tk = 0;                                  // 40 KB
  const size_t off_posA = off_tk + (size_t)BB * NBB * TOPKN * 4;
  const size_t off_posI = off_posA + 4096;
  const size_t off_resj = off_posI + 4096;                  // 40 KB
  const size_t off_resAl = off_resj + (size_t)BB * NBB * TOPKN * 4;

  int* tk = (int*)(ws + off_tk);
  int* posA = (int*)(ws + off_posA);
  int* posI = (int*)(ws + off_posI);
  int* resj = (int*)(ws + off_resj);
  float* resAl = (float*)(ws + off_resAl);

  dim3 g1(NBB, BB);
  gt_topk_kernel<<<g1, 256, 0, stream>>>(pred_scores, pred_boxes, gt_labels,
                                         gt_boxes, gt_mask, tk, posA, posI,
                                         out);

  dim3 g2(NBB, BB);
  assign_sparse_kernel<<<g2, 64, 0, stream>>>(
      pred_scores, pred_boxes, anchor_points, gt_labels, gt_boxes, gt_mask,
      tk, resj, resAl, posA, posI);

  const int ncand = BB * NBB * TOPKN;
  scatter_out_kernel<<<(ncand + 255) / 256, 256, 0, stream>>>(
      gt_labels, gt_boxes, tk, resj, resAl, posA, posI, out);
}